// Round 12
// baseline (136.867 us; speedup 1.0000x reference)
//
#include <hip/hip_runtime.h>
#include <hip/hip_bf16.h>

#define DEV_INLINE __device__ __forceinline__

constexpr int Nn   = 10000;     // nodes per batch
constexpr int NT   = 20000;     // B*N
constexpr int Me   = 320000;    // template edges
constexpr int STRIDE = 96;      // padded CSR slot stride (max in-degree ~60)
constexpr float NEG = 0.2f;

typedef float  f32x4  __attribute__((ext_vector_type(4)));
typedef short  bf16x8 __attribute__((ext_vector_type(8)));

DEV_INLINE float leaky(float x){ return x >= 0.f ? x : NEG*x; }

DEV_INLINE ushort f2bf(float v){
  __hip_bfloat16 h = __float2bfloat16(v);
  return *reinterpret_cast<ushort*>(&h);
}
DEV_INLINE float bf2f(ushort u){
  uint x = ((uint)u) << 16;
  return __uint_as_float(x);
}
DEV_INLINE float sel4(float4 w, int h){
  return h < 2 ? (h == 0 ? w.x : w.y) : (h == 2 ? w.z : w.w);
}
DEV_INLINE float red16(float v){
  v += __shfl_xor(v, 1); v += __shfl_xor(v, 2);
  v += __shfl_xor(v, 4); v += __shfl_xor(v, 8);
  return v;
}
DEV_INLINE float red32(float v){
  v += __shfl_xor(v, 1); v += __shfl_xor(v, 2);
  v += __shfl_xor(v, 4); v += __shfl_xor(v, 8);
  v += __shfl_xor(v, 16);
  return v;
}

// ---------------- generic small MLP stage + fused utility tail-blocks ----------------
// tails after mlpBlocks: [zblk] zero zbuf | [xblk] f32->bf16 convert | [mblk] M=w3@G | [1] bG=b3@G
template<int K>
__global__ __launch_bounds__(256) void k_mlp(const float* __restrict__ in,
    const float* __restrict__ W, const float* __restrict__ bias,
    float* __restrict__ out, int OD, int doAct, int mlpBlocks,
    int* __restrict__ zbuf, int zn, int zblk,
    const float* __restrict__ xsrc, ushort* __restrict__ xdst, int xn4, int xblk,
    const float* __restrict__ w3, const float* __restrict__ G,
    float* __restrict__ M, const float* __restrict__ b3, float* __restrict__ bG,
    int mblk){
  if ((int)blockIdx.x >= mlpBlocks){
    int b2 = blockIdx.x - mlpBlocks;
    if (b2 < zblk){
      int i = b2*256 + threadIdx.x;
      if (i < zn) zbuf[i] = 0;
    } else if ((b2 -= zblk) < xblk){
      int i4 = b2*256 + threadIdx.x;
      if (i4 < xn4){
        float4 v = ((const float4*)xsrc)[i4];
        ushort4 o;
        o.x = f2bf(v.x); o.y = f2bf(v.y); o.z = f2bf(v.z); o.w = f2bf(v.w);
        ((ushort4*)xdst)[i4] = o;
      }
    } else if ((b2 -= xblk) < mblk){
      // M[k][j] = sum_m w3[k][m]*G[m][j]; 2 k-rows per block
      int k = b2*2 + (threadIdx.x >> 7);
      int j = threadIdx.x & 127;
      float a = 0.f;
      for (int m=0; m<128; m++) a += w3[k*128 + m] * G[m*128 + j];
      M[(size_t)k*128 + j] = a;
    } else {
      if (threadIdx.x < 128){
        int j = threadIdx.x;
        float a = 0.f;
        for (int m=0; m<128; m++) a += b3[m] * G[m*128 + j];
        bG[j] = a;
      }
    }
    return;
  }
  int wave = threadIdx.x >> 6, lane = threadIdx.x & 63;
  int o = blockIdx.x*4 + wave;
  if (o >= 2*OD) return;
  int b = (o >= OD) ? 1 : 0;
  int j = o - b*OD;
  const float* __restrict__ ip = in + b*K;
  float acc = 0.f;
  #pragma unroll 2
  for (int k = lane; k < K; k += 64) acc += ip[k] * W[(size_t)k*OD + j];
  #pragma unroll
  for (int off = 32; off; off >>= 1) acc += __shfl_xor(acc, off);
  if (lane == 0){
    float v = acc + (bias ? bias[j] : 0.f);
    out[o] = doAct ? leaky(v) : v;
  }
}

// ---- MFMA ht0: ht0[b,row,c](bf16) = x_bf16[row,:64] @ gw0[:64,c] + styleW0[b,c],
//      fused layer-0 logits; blocks >= mbBlocks do the CSR scatter instead. ----
__global__ __launch_bounds__(256) void k_ht0_mfma(const ushort* __restrict__ xb,
    const float* __restrict__ gw0, const float* __restrict__ styleW0,
    const float* __restrict__ a_s, const float* __restrict__ a_d,
    ushort* __restrict__ ht0, float* __restrict__ alS, float* __restrict__ alD,
    int mbBlocks, const int* __restrict__ eidx, int* __restrict__ cnt,
    ushort* __restrict__ slot){
  if ((int)blockIdx.x >= mbBlocks){
    int e = (blockIdx.x - mbBlocks)*256 + threadIdx.x;
    if (e < Me){
      int s = eidx[e], d = eidx[Me + e];
      int p = atomicAdd(&cnt[d], 1);
      if (p < STRIDE) slot[(size_t)d*STRIDE + p] = (ushort)s;
    }
    return;
  }
  __shared__ ushort bt[128*64];           // Bt[c][k], XOR-swizzled
  __shared__ float stycS[2][4], stycD[2][4];
  int t = threadIdx.x;
  int wid = t >> 6, lane = t & 63, l15 = lane & 15, g = lane >> 4;
  int mbase = blockIdx.x*128 + wid*32;

  // A fragments: rows of x_bf16 (K=64 -> 2 k-steps)
  bf16x8 afr[2][2];
  #pragma unroll
  for (int mf=0; mf<2; mf++){
    int row = mbase + mf*16 + l15;
    int rc = row < Nn ? row : Nn-1;
    const ushort* ap = xb + (size_t)rc*64 + g*8;
    #pragma unroll
    for (int ks=0; ks<2; ks++)
      afr[mf][ks] = *(const bf16x8*)(ap + ks*32);
  }

  // stage gw0[:64,:] -> LDS transposed bf16, swizzled
  for (int idx = t; idx < 64*128; idx += 256){
    int k = idx >> 7, c = idx & 127;
    uint byte = ((uint)(c*64 + k) << 1) ^ ((uint)(c&7) << 4);
    *(ushort*)((char*)bt + byte) = f2bf(gw0[k*128 + c]);
  }

  // style-const logits per (batch, head): threads t<128 cover c=t
  if (t < 128){
    int c = t, h = c >> 5;
    float as_c = a_s[c], ad_c = a_d[c];
    float s0 = styleW0[c], s1 = styleW0[128 + c];
    float v0s = red32(s0*as_c), v0d = red32(s0*ad_c);
    float v1s = red32(s1*as_c), v1d = red32(s1*ad_c);
    if ((lane & 31) == 0){
      stycS[0][h] = v0s; stycD[0][h] = v0d;
      stycS[1][h] = v1s; stycD[1][h] = v1d;
    }
  }
  __syncthreads();

  f32x4 acc[2][8];
  #pragma unroll
  for (int mf=0; mf<2; mf++)
    #pragma unroll
    for (int nf=0; nf<8; nf++) acc[mf][nf] = (f32x4){0.f,0.f,0.f,0.f};

  #pragma unroll
  for (int ks=0; ks<2; ks++){
    int kb = ks*32 + g*8;
    bf16x8 bfr[8];
    #pragma unroll
    for (int nf=0; nf<8; nf++){
      int c = nf*16 + l15;
      uint byte = ((uint)(c*64 + kb) << 1) ^ ((uint)(c&7) << 4);
      bfr[nf] = *(const bf16x8*)((const char*)bt + byte);
    }
    #pragma unroll
    for (int mf=0; mf<2; mf++)
      #pragma unroll
      for (int nf=0; nf<8; nf++)
        acc[mf][nf] = __builtin_amdgcn_mfma_f32_16x16x32_bf16(
            afr[mf][ks], bfr[nf], acc[mf][nf], 0, 0, 0);
  }

  // epilogue: dual-batch store + fused logits
  float sw0[8], sw1[8], as_v[8], ad_v[8];
  #pragma unroll
  for (int nf=0; nf<8; nf++){
    int c = nf*16 + l15;
    sw0[nf] = styleW0[c]; sw1[nf] = styleW0[128 + c];
    as_v[nf] = a_s[c];    ad_v[nf] = a_d[c];
  }
  #pragma unroll
  for (int mf=0; mf<2; mf++){
    int rbase = mbase + mf*16 + g*4;
    #pragma unroll
    for (int r=0; r<4; r++){
      int row = rbase + r;
      bool ok = (row < Nn);
      #pragma unroll
      for (int nf=0; nf<8; nf++){
        int c = nf*16 + l15;
        if (ok){
          float v = acc[mf][nf][r];
          ht0[(size_t)row*128 + c]      = f2bf(v + sw0[nf]);
          ht0[(size_t)(Nn+row)*128 + c] = f2bf(v + sw1[nf]);
        }
      }
      float ps0 = acc[mf][0][r]*as_v[0] + acc[mf][1][r]*as_v[1];
      float ps1 = acc[mf][2][r]*as_v[2] + acc[mf][3][r]*as_v[3];
      float ps2 = acc[mf][4][r]*as_v[4] + acc[mf][5][r]*as_v[5];
      float ps3 = acc[mf][6][r]*as_v[6] + acc[mf][7][r]*as_v[7];
      float pd0 = acc[mf][0][r]*ad_v[0] + acc[mf][1][r]*ad_v[1];
      float pd1 = acc[mf][2][r]*ad_v[2] + acc[mf][3][r]*ad_v[3];
      float pd2 = acc[mf][4][r]*ad_v[4] + acc[mf][5][r]*ad_v[5];
      float pd3 = acc[mf][6][r]*ad_v[6] + acc[mf][7][r]*ad_v[7];
      ps0 = red16(ps0); ps1 = red16(ps1); ps2 = red16(ps2); ps3 = red16(ps3);
      pd0 = red16(pd0); pd1 = red16(pd1); pd2 = red16(pd2); pd3 = red16(pd3);
      if (l15 == 0 && ok){
        *(float4*)(alS + (size_t)row*4) = make_float4(
            ps0 + stycS[0][0], ps1 + stycS[0][1], ps2 + stycS[0][2], ps3 + stycS[0][3]);
        *(float4*)(alD + (size_t)row*4) = make_float4(
            pd0 + stycD[0][0], pd1 + stycD[0][1], pd2 + stycD[0][2], pd3 + stycD[0][3]);
        *(float4*)(alS + (size_t)(Nn+row)*4) = make_float4(
            ps0 + stycS[1][0], ps1 + stycS[1][1], ps2 + stycS[1][2], ps3 + stycS[1][3]);
        *(float4*)(alD + (size_t)(Nn+row)*4) = make_float4(
            pd0 + stycD[1][0], pd1 + stycD[1][1], pd2 + stycD[1][2], pd3 + stycD[1][3]);
      }
    }
  }
}

// ---- MFMA matmul + fused attention logits ----
template<int NCOL, int LDO, int NF, int NHEAD>
__global__ __launch_bounds__(256) void k_mm_mfma(const ushort* __restrict__ A,
    const float* __restrict__ W, ushort* __restrict__ out,
    const float* __restrict__ a_s, const float* __restrict__ a_d,
    float* __restrict__ alS, float* __restrict__ alD, int M){
  constexpr int NCOLP = NF*16;
  __shared__ ushort bt[NCOLP*128];  // Bt[c][k], XOR-swizzled
  int t = threadIdx.x;
  int wid = t >> 6, lane = t & 63, l15 = lane & 15, g = lane >> 4;
  int mbase = blockIdx.x*128 + wid*32;

  bf16x8 afr[2][4];
  #pragma unroll
  for (int mf=0; mf<2; mf++){
    int row = mbase + mf*16 + l15;
    int rc = row < M ? row : M-1;
    const ushort* ap = A + (size_t)rc*128 + g*8;
    #pragma unroll
    for (int ks=0; ks<4; ks++)
      afr[mf][ks] = *(const bf16x8*)(ap + ks*32);
  }

  for (int idx = t; idx < 128*NCOLP; idx += 256){
    int k = idx / NCOLP, c = idx % NCOLP;
    float v = (c < NCOL) ? W[k*NCOL + c] : 0.f;
    uint byte = ((uint)(c*128 + k) << 1) ^ ((uint)(c&7) << 4);
    *(ushort*)((char*)bt + byte) = f2bf(v);
  }
  __syncthreads();

  f32x4 acc[2][NF];
  #pragma unroll
  for (int mf=0; mf<2; mf++)
    #pragma unroll
    for (int nf=0; nf<NF; nf++) acc[mf][nf] = (f32x4){0.f,0.f,0.f,0.f};

  #pragma unroll
  for (int ks=0; ks<4; ks++){
    int kb = ks*32 + g*8;
    bf16x8 bfr[NF];
    #pragma unroll
    for (int nf=0; nf<NF; nf++){
      int c = nf*16 + l15;
      uint byte = ((uint)(c*128 + kb) << 1) ^ ((uint)(c&7) << 4);
      bfr[nf] = *(const bf16x8*)((const char*)bt + byte);
    }
    #pragma unroll
    for (int mf=0; mf<2; mf++)
      #pragma unroll
      for (int nf=0; nf<NF; nf++)
        acc[mf][nf] = __builtin_amdgcn_mfma_f32_16x16x32_bf16(
            afr[mf][ks], bfr[nf], acc[mf][nf], 0, 0, 0);
  }

  // C/D layout: col = lane&15, row = (lane>>4)*4 + r
  #pragma unroll
  for (int mf=0; mf<2; mf++){
    int rbase = mbase + mf*16 + g*4;
    #pragma unroll
    for (int nf=0; nf<NF; nf++){
      int c = nf*16 + l15;
      if (c < LDO){
        #pragma unroll
        for (int r=0; r<4; r++){
          int row = rbase + r;
          if (row < M) out[(size_t)row*LDO + c] = (c < NCOL) ? f2bf(acc[mf][nf][r]) : (ushort)0;
        }
      }
    }
  }

  // fused per-row attention logits
  float as_v[NF], ad_v[NF];
  #pragma unroll
  for (int nf=0; nf<NF; nf++){
    int c = nf*16 + l15;
    as_v[nf] = (c < NCOL) ? a_s[c] : 0.f;
    ad_v[nf] = (c < NCOL) ? a_d[c] : 0.f;
  }
  #pragma unroll
  for (int mf=0; mf<2; mf++){
    #pragma unroll
    for (int r=0; r<4; r++){
      int row = mbase + mf*16 + g*4 + r;
      if (NHEAD == 4){
        float ps0 = acc[mf][0][r]*as_v[0] + acc[mf][1][r]*as_v[1];
        float ps1 = acc[mf][2][r]*as_v[2] + acc[mf][3][r]*as_v[3];
        float ps2 = acc[mf][4][r]*as_v[4] + acc[mf][5][r]*as_v[5];
        float ps3 = acc[mf][6][r]*as_v[6] + acc[mf][7][r]*as_v[7];
        float pd0 = acc[mf][0][r]*ad_v[0] + acc[mf][1][r]*ad_v[1];
        float pd1 = acc[mf][2][r]*ad_v[2] + acc[mf][3][r]*ad_v[3];
        float pd2 = acc[mf][4][r]*ad_v[4] + acc[mf][5][r]*ad_v[5];
        float pd3 = acc[mf][6][r]*ad_v[6] + acc[mf][7][r]*ad_v[7];
        ps0 = red16(ps0); ps1 = red16(ps1); ps2 = red16(ps2); ps3 = red16(ps3);
        pd0 = red16(pd0); pd1 = red16(pd1); pd2 = red16(pd2); pd3 = red16(pd3);
        if (l15 == 0 && row < M){
          *(float4*)(alS + (size_t)row*4) = make_float4(ps0, ps1, ps2, ps3);
          *(float4*)(alD + (size_t)row*4) = make_float4(pd0, pd1, pd2, pd3);
        }
      } else {
        float ps = 0.f, pd = 0.f;
        #pragma unroll
        for (int nf=0; nf<NF; nf++){
          ps += acc[mf][nf][r]*as_v[nf];
          pd += acc[mf][nf][r]*ad_v[nf];
        }
        ps = red16(ps); pd = red16(pd);
        if (l15 == 0 && row < M){
          alS[row] = ps; alD[row] = pd;
        }
      }
    }
  }
}

// ---------------- GAT aggregation layer 0/1: edge-pair lanes, 4 cols/lane ----------------
// sub = lane>>5 picks even/odd edges; li = lane&31 covers cols 4*li..4*li+3 (one 8B load).
__global__ __launch_bounds__(256) void k_gat128(const ushort* __restrict__ ht,
    const float* __restrict__ alS, const float* __restrict__ alD,
    const int* __restrict__ deg, const ushort* __restrict__ slot,
    const float* __restrict__ gb, const float* __restrict__ lng,
    const float* __restrict__ lnb, ushort* __restrict__ outH, int n){
  __shared__ float wbuf[4][4][68];   // [wave][head][edge] padded
  __shared__ int   sbuf[4][64];
  int wave = threadIdx.x >> 6, lane = threadIdx.x & 63;
  int dd = blockIdx.x*4 + wave;
  if (dd >= n) return;
  int tr  = (dd >= Nn) ? dd - Nn : dd;
  int off = (dd >= Nn) ? Nn : 0;
  int sub = lane >> 5, li = lane & 31;
  int c0 = li*4;
  int h  = li >> 3;                 // head of cols c0..c0+3
  float4 ald4 = *(const float4*)(alD + dd*4);
  int dg = deg[tr]; if (dg > STRIDE) dg = STRIDE;
  int begin = tr*STRIDE, end = begin + dg;

  // self-loop term (added by sub==0 half only)
  float4 asl = *(const float4*)(alS + dd*4);
  float4 wsl;
  wsl.x = __expf(leaky(asl.x + ald4.x));
  wsl.y = __expf(leaky(asl.y + ald4.y));
  wsl.z = __expf(leaky(asl.z + ald4.z));
  wsl.w = __expf(leaky(asl.w + ald4.w));
  float es = sel4(wsl, h);
  float acc0=0.f, acc1=0.f, acc2=0.f, acc3=0.f, den=0.f;
  if (sub == 0){
    ushort4 sv = *(const ushort4*)(ht + (size_t)dd*128 + c0);
    den = es;
    acc0 = es * bf2f(sv.x); acc1 = es * bf2f(sv.y);
    acc2 = es * bf2f(sv.z); acc3 = es * bf2f(sv.w);
  }

  const ushort* __restrict__ htp = ht + c0;

  for (int j = begin; j < end; j += 64){
    int nc = min(64, end - j);
    // phase A: one edge per lane -> per-head weight arrays in wave-private LDS
    if (lane < nc){
      int s = (int)slot[j + lane] + off;
      float4 as4 = *(const float4*)(alS + s*4);
      wbuf[wave][0][lane] = __expf(leaky(as4.x + ald4.x));
      wbuf[wave][1][lane] = __expf(leaky(as4.y + ald4.y));
      wbuf[wave][2][lane] = __expf(leaky(as4.z + ald4.z));
      wbuf[wave][3][lane] = __expf(leaky(as4.w + ald4.w));
      sbuf[wave][lane] = s;
    }
    // phase B: edge pairs; this half handles edges q+2u+sub
    const float* __restrict__ wh = wbuf[wave][h];
    int q = 0;
    for (; q + 8 <= nc; q += 8){
      int sv[4]; float wv[4];
      #pragma unroll
      for (int u=0;u<4;u++){ int e = q + 2*u + sub; sv[u] = sbuf[wave][e]; wv[u] = wh[e]; }
      ushort4 hv[4];
      #pragma unroll
      for (int u=0;u<4;u++) hv[u] = *(const ushort4*)(htp + (size_t)sv[u]*128);
      #pragma unroll
      for (int u=0;u<4;u++){
        den  += wv[u];
        acc0 += wv[u] * bf2f(hv[u].x);
        acc1 += wv[u] * bf2f(hv[u].y);
        acc2 += wv[u] * bf2f(hv[u].z);
        acc3 += wv[u] * bf2f(hv[u].w);
      }
    }
    for (; q < nc; q += 2){
      int e = q + sub;
      if (e < nc){
        int s = sbuf[wave][e];
        float w = wh[e];
        ushort4 hv = *(const ushort4*)(htp + (size_t)s*128);
        den  += w;
        acc0 += w * bf2f(hv.x); acc1 += w * bf2f(hv.y);
        acc2 += w * bf2f(hv.z); acc3 += w * bf2f(hv.w);
      }
    }
  }
  // combine even/odd halves (lanes l and l+32 hold partial sums of same cols)
  acc0 += __shfl_xor(acc0, 32); acc1 += __shfl_xor(acc1, 32);
  acc2 += __shfl_xor(acc2, 32); acc3 += __shfl_xor(acc3, 32);
  den  += __shfl_xor(den, 32);

  float idn = 1.f / (den + 1e-16f);
  float4 gbv = *(const float4*)(gb + c0);
  float v0 = acc0*idn + gbv.x;
  float v1 = acc1*idn + gbv.y;
  float v2 = acc2*idn + gbv.z;
  float v3 = acc3*idn + gbv.w;

  // LayerNorm: each 32-lane half independently holds all 128 cols (4/lane)
  float sum = v0+v1+v2+v3;
  float sq  = v0*v0+v1*v1+v2*v2+v3*v3;
  sum = red32(sum); sq = red32(sq);
  float mu  = sum * (1.f/128.f);
  float var = sq  * (1.f/128.f) - mu*mu;
  float inv = rsqrtf(var + 1e-5f);
  float4 lg = *(const float4*)(lng + c0);
  float4 lb = *(const float4*)(lnb + c0);
  if (sub == 0){
    float y0 = (v0 - mu)*inv*lg.x + lb.x;
    float y1 = (v1 - mu)*inv*lg.y + lb.y;
    float y2 = (v2 - mu)*inv*lg.z + lb.z;
    float y3 = (v3 - mu)*inv*lg.w + lb.w;
    uint2 ow;
    ow.x = (uint)f2bf(leaky(y0)) | ((uint)f2bf(leaky(y1)) << 16);
    ow.y = (uint)f2bf(leaky(y2)) | ((uint)f2bf(leaky(y3)) << 16);
    *(uint2*)(outH + (size_t)dd*128 + c0) = ow;
  }
}

// ---------------- GAT output layer (1 head, 67 cols), bf16 gathers + residual ----------------
__global__ __launch_bounds__(256) void k_gat_out(const ushort* __restrict__ ht2,
    const float* __restrict__ alS, const float* __restrict__ alD,
    const int* __restrict__ deg, const ushort* __restrict__ slot,
    const float* __restrict__ gb2, const float* __restrict__ x,
    const float* __restrict__ pos, float* __restrict__ out, int n){
  __shared__ float wbuf[4][64];
  __shared__ int   sbuf[4][64];
  int wave = threadIdx.x >> 6, lane = threadIdx.x & 63;
  int dd = blockIdx.x*4 + wave;
  if (dd >= n) return;
  int tr  = (dd >= Nn) ? dd - Nn : dd;
  int off = (dd >= Nn) ? Nn : 0;
  int c0 = lane*2;
  bool act = (c0 < 67);             // lane < 34
  float ald = alD[dd];
  int dg = deg[tr]; if (dg > STRIDE) dg = STRIDE;
  int begin = tr*STRIDE, end = begin + dg;

  // self-loop term
  float wsl = __expf(leaky(alS[dd] + ald));
  float den  = wsl;
  uint sv0 = act ? *(const uint*)(ht2 + (size_t)dd*68 + c0) : 0u;
  float acc0 = wsl * bf2f((ushort)(sv0 & 0xffff));
  float acc1 = wsl * bf2f((ushort)(sv0 >> 16));

  const ushort* __restrict__ h2p = ht2 + c0;

  for (int j = begin; j < end; j += 64){
    int nc = min(64, end - j);
    if (lane < nc){
      int s = (int)slot[j + lane] + off;
      wbuf[wave][lane] = __expf(leaky(alS[s] + ald));
      sbuf[wave][lane] = s;
    }
    int q = 0;
    for (; q + 8 <= nc; q += 8){
      int sv[8]; float wv[8];
      #pragma unroll
      for (int u=0;u<8;u++){ sv[u] = sbuf[wave][q+u]; wv[u] = wbuf[wave][q+u]; }
      uint hv[8];
      #pragma unroll
      for (int u=0;u<8;u++) hv[u] = act ? *(const uint*)(h2p + (size_t)sv[u]*68) : 0u;
      #pragma unroll
      for (int u=0;u<8;u++){
        den  += wv[u];
        acc0 += wv[u] * bf2f((ushort)(hv[u] & 0xffff));
        acc1 += wv[u] * bf2f((ushort)(hv[u] >> 16));
      }
    }
    for (; q < nc; q++){
      int s = sbuf[wave][q]; float w = wbuf[wave][q];
      uint hv = act ? *(const uint*)(h2p + (size_t)s*68) : 0u;
      den  += w;
      acc0 += w * bf2f((ushort)(hv & 0xffff));
      acc1 += w * bf2f((ushort)(hv >> 16));
    }
  }
  if (!act) return;
  float idn = 1.f / (den + 1e-16f);
  int i = tr;
  int c1 = c0 + 1;
  float v0 = acc0*idn + gb2[c0];
  if (c0 < 3) out[NT*64 + dd*3 + c0] = pos[i*3 + c0] + v0;
  else        out[dd*64 + (c0-3)]    = x[i*64 + (c0-3)] + v0;
  if (c1 < 67){
    float v1 = acc1*idn + gb2[c1];
    if (c1 < 3) out[NT*64 + dd*3 + c1] = pos[i*3 + c1] + v1;
    else        out[dd*64 + (c1-3)]    = x[i*64 + (c1-3)] + v1;
  }
}

extern "C" void kernel_launch(void* const* d_in, const int* in_sizes, int n_in,
                              void* d_out, int out_size, void* d_ws, size_t ws_size,
                              hipStream_t stream){
  const float* z    = (const float*)d_in[0];
  const float* x    = (const float*)d_in[1];
  const float* pos  = (const float*)d_in[2];
  const int*   eidx = (const int*)  d_in[3];
  const float* w1   = (const float*)d_in[4];
  const float* b1   = (const float*)d_in[5];
  const float* w2   = (const float*)d_in[6];
  const float* b2   = (const float*)d_in[7];
  const float* w3   = (const float*)d_in[8];
  const float* b3   = (const float*)d_in[9];
  const float* gw0  = (const float*)d_in[10];
  const float* ga0s = (const float*)d_in[11];
  const float* ga0d = (const float*)d_in[12];
  const float* gb0  = (const float*)d_in[13];
  const float* gw1  = (const float*)d_in[14];
  const float* ga1s = (const float*)d_in[15];
  const float* ga1d = (const float*)d_in[16];
  const float* gb1  = (const float*)d_in[17];
  const float* gw2  = (const float*)d_in[18];
  const float* ga2s = (const float*)d_in[19];
  const float* ga2d = (const float*)d_in[20];
  const float* gb2  = (const float*)d_in[21];
  const float* ln0g = (const float*)d_in[22];
  const float* ln0b = (const float*)d_in[23];
  const float* ln1g = (const float*)d_in[24];
  const float* ln1b = (const float*)d_in[25];
  float* out = (float*)d_out;

  float* ws       = (float*)d_ws;
  float* styleW0  = ws;                  // 256
  float* s1buf    = ws + 256;            // 512
  float* s2buf    = s1buf + 512;         // 1024
  float* Mbuf     = s2buf + 1024;        // 512*128
  float* bGbuf    = Mbuf + 512*128;      // 128
  float* alS      = bGbuf + 128;         // 80000
  float* alD      = alS + 80000;         // 80000
  ushort* htA     = (ushort*)(alD + 80000);  // NT*128 bf16
  ushort* htB     = htA + (size_t)NT*128;    // NT*128 bf16
  ushort* ht2c    = htB + (size_t)NT*128;    // NT*68 bf16
  ushort* xb      = ht2c + (size_t)NT*68;    // Nn*64 bf16 (x converted)
  int*   cnt      = (int*)(xb + (size_t)Nn*64);   // Nn (degree)
  ushort* slot    = (ushort*)(cnt + Nn);          // Nn*STRIDE (padded CSR)

  const float* G = gw0 + 64*128;           // style half of gw0

  // dispatch 1: style stage1 + tails {zero cnt, x->bf16, M=w3@G, bG=b3@G}
  const int ZB = (Nn + 255)/256;           // 40
  const int XB = (Nn*64/4 + 255)/256;      // 625
  const int MBk = 256;                     // 512 k-rows / 2 per block
  k_mlp<128><<<128 + ZB + XB + MBk + 1, 256, 0, stream>>>(
      z, w1, b1, s1buf, 256, 1, 128,
      cnt, Nn, ZB, x, xb, Nn*64/4, XB,
      w3, G, Mbuf, b3, bGbuf, MBk);
  // stage 2
  k_mlp<256><<<256, 256, 0, stream>>>(s1buf, w2, b2, s2buf, 512, 1, 256,
      nullptr, 0, 0, nullptr, nullptr, 0, 0, nullptr, nullptr, nullptr, nullptr, nullptr, 0);
  // fused stages 3+4: styleW0 = s2 @ M + bG
  k_mlp<512><<<64, 256, 0, stream>>>(s2buf, Mbuf, bGbuf, styleW0, 128, 0, 64,
      nullptr, 0, 0, nullptr, nullptr, 0, 0, nullptr, nullptr, nullptr, nullptr, nullptr, 0);

  const int MB0 = (Nn+127)/128;            // 79 mfma blocks
  const int EB  = (Me+255)/256;            // 1250 scatter blocks
  // layer 0: ht0 MFMA + fused logits, with CSR scatter in extra blocks
  k_ht0_mfma<<<MB0 + EB, 256, 0, stream>>>(xb, gw0, styleW0, ga0s, ga0d,
                                           htA, alS, alD, MB0, eidx, cnt, slot);
  k_gat128<<<(NT+3)/4, 256, 0, stream>>>(htA, alS, alD, cnt, slot,
                                         gb0, ln0g, ln0b, htB, NT);
  // layer 1 (matmul + fused logits)
  const int MB = (NT+127)/128;
  k_mm_mfma<128,128,8,4><<<MB, 256, 0, stream>>>(htB, gw1, htA, ga1s, ga1d, alS, alD, NT);
  k_gat128<<<(NT+3)/4, 256, 0, stream>>>(htA, alS, alD, cnt, slot,
                                         gb1, ln1g, ln1b, htB, NT);
  // layer 2 (matmul + fused logits, 1 head; then fused residual + final write)
  k_mm_mfma<67,68,5,1><<<MB, 256, 0, stream>>>(htB, gw2, ht2c, ga2s, ga2d, alS, alD, NT);
  k_gat_out<<<(NT+3)/4, 256, 0, stream>>>(ht2c, alS, alD, cnt, slot,
                                          gb2, x, pos, out, NT);
}

// Round 15
// 129.633 us; speedup vs baseline: 1.0558x; 1.0558x over previous
//
#include <hip/hip_runtime.h>
#include <hip/hip_bf16.h>

#define DEV_INLINE __device__ __forceinline__

constexpr int Nn   = 10000;     // nodes per batch
constexpr int NT   = 20000;     // B*N
constexpr int Me   = 320000;    // template edges
constexpr int STRIDE = 96;      // padded CSR slot stride (max in-degree ~60)
constexpr float NEG = 0.2f;

typedef float  f32x4  __attribute__((ext_vector_type(4)));
typedef float  f32x2  __attribute__((ext_vector_type(2)));
typedef short  bf16x8 __attribute__((ext_vector_type(8)));

DEV_INLINE float leaky(float x){ return x >= 0.f ? x : NEG*x; }

DEV_INLINE ushort f2bf(float v){
  __hip_bfloat16 h = __float2bfloat16(v);
  return *reinterpret_cast<ushort*>(&h);
}
DEV_INLINE float bf2f(ushort u){
  uint x = ((uint)u) << 16;
  return __uint_as_float(x);
}

// ---- fp8 e4m3 (OCP) encode/decode, HW cvt with manual fallback ----
DEV_INLINE unsigned char f2f8(float v){
#if __has_builtin(__builtin_amdgcn_cvt_pk_fp8_f32)
  return (unsigned char)(__builtin_amdgcn_cvt_pk_fp8_f32(v, v, 0, false) & 0xFF);
#else
  uint u = __float_as_uint(v);
  uint s = (u >> 24) & 0x80u;
  uint au = u & 0x7FFFFFFFu;
  if (au >= 0x43E00000u) return (unsigned char)(s | 0x7Eu);   // clamp to 448
  uint au2 = au + 0x0007FFFFu + ((au >> 20) & 1u);            // RNE at bit 20
  int e = (int)(au2 >> 23) - 120;
  if (e <= 0) return (unsigned char)s;                        // flush tiny
  uint r = ((uint)e << 3) | ((au2 >> 20) & 7u);
  if (r >= 0x7Fu) r = 0x7Eu;
  return (unsigned char)(s | r);
#endif
}
template<bool HI>
DEV_INLINE f32x2 f8x2f(uint p){
#if __has_builtin(__builtin_amdgcn_cvt_pk_f32_fp8)
  return __builtin_amdgcn_cvt_pk_f32_fp8((int)p, HI);
#else
  uint b0 = HI ? ((p >> 16) & 0xFFu) : (p & 0xFFu);
  uint b1 = HI ? ((p >> 24) & 0xFFu) : ((p >> 8) & 0xFFu);
  f32x2 r;
  uint m0 = b0 & 0x7Fu, m1 = b1 & 0x7Fu;
  uint f0 = (m0 >= 8) ? ((m0 + 960u) << 20) : 0u;
  uint f1 = (m1 >= 8) ? ((m1 + 960u) << 20) : 0u;
  f0 |= (b0 & 0x80u) << 24; f1 |= (b1 & 0x80u) << 24;
  r.x = __uint_as_float(f0); r.y = __uint_as_float(f1);
  return r;
#endif
}

DEV_INLINE float sel4(float4 w, int h){
  return h < 2 ? (h == 0 ? w.x : w.y) : (h == 2 ? w.z : w.w);
}
DEV_INLINE float red16(float v){
  v += __shfl_xor(v, 1); v += __shfl_xor(v, 2);
  v += __shfl_xor(v, 4); v += __shfl_xor(v, 8);
  return v;
}
DEV_INLINE float red32(float v){
  v += __shfl_xor(v, 1); v += __shfl_xor(v, 2);
  v += __shfl_xor(v, 4); v += __shfl_xor(v, 8);
  v += __shfl_xor(v, 16);
  return v;
}

// ---------------- generic small MLP stage + fused utility tail-blocks ----------------
// tails after mlpBlocks: [zblk] zero zbuf | [xblk] f32->bf16 convert | [mblk] M=w3@G | [1] bG=b3@G
template<int K>
__global__ __launch_bounds__(256) void k_mlp(const float* __restrict__ in,
    const float* __restrict__ W, const float* __restrict__ bias,
    float* __restrict__ out, int OD, int doAct, int mlpBlocks,
    int* __restrict__ zbuf, int zn, int zblk,
    const float* __restrict__ xsrc, ushort* __restrict__ xdst, int xn4, int xblk,
    const float* __restrict__ w3, const float* __restrict__ G,
    float* __restrict__ M, const float* __restrict__ b3, float* __restrict__ bG,
    int mblk){
  if ((int)blockIdx.x >= mlpBlocks){
    int b2 = blockIdx.x - mlpBlocks;
    if (b2 < zblk){
      int i = b2*256 + threadIdx.x;
      if (i < zn) zbuf[i] = 0;
    } else if ((b2 -= zblk) < xblk){
      int i4 = b2*256 + threadIdx.x;
      if (i4 < xn4){
        float4 v = ((const float4*)xsrc)[i4];
        ushort4 o;
        o.x = f2bf(v.x); o.y = f2bf(v.y); o.z = f2bf(v.z); o.w = f2bf(v.w);
        ((ushort4*)xdst)[i4] = o;
      }
    } else if ((b2 -= xblk) < mblk){
      int k = b2*2 + (threadIdx.x >> 7);
      int j = threadIdx.x & 127;
      float a = 0.f;
      for (int m=0; m<128; m++) a += w3[k*128 + m] * G[m*128 + j];
      M[(size_t)k*128 + j] = a;
    } else {
      if (threadIdx.x < 128){
        int j = threadIdx.x;
        float a = 0.f;
        for (int m=0; m<128; m++) a += b3[m] * G[m*128 + j];
        bG[j] = a;
      }
    }
    return;
  }
  int wave = threadIdx.x >> 6, lane = threadIdx.x & 63;
  int o = blockIdx.x*4 + wave;
  if (o >= 2*OD) return;
  int b = (o >= OD) ? 1 : 0;
  int j = o - b*OD;
  const float* __restrict__ ip = in + b*K;
  float acc = 0.f;
  #pragma unroll 2
  for (int k = lane; k < K; k += 64) acc += ip[k] * W[(size_t)k*OD + j];
  #pragma unroll
  for (int off = 32; off; off >>= 1) acc += __shfl_xor(acc, off);
  if (lane == 0){
    float v = acc + (bias ? bias[j] : 0.f);
    out[o] = doAct ? leaky(v) : v;
  }
}

// ---- MFMA ht0: htA[b,row,c](fp8) = x_bf16[row,:64] @ gw0[:64,c] + styleW0[b,c],
//      fused layer-0 logits; blocks >= mbBlocks do the CSR scatter instead. ----
__global__ __launch_bounds__(256) void k_ht0_mfma(const ushort* __restrict__ xb,
    const float* __restrict__ gw0, const float* __restrict__ styleW0,
    const float* __restrict__ a_s, const float* __restrict__ a_d,
    unsigned char* __restrict__ ht0, float* __restrict__ alS, float* __restrict__ alD,
    int mbBlocks, const int* __restrict__ eidx, int* __restrict__ cnt,
    ushort* __restrict__ slot){
  if ((int)blockIdx.x >= mbBlocks){
    int e = (blockIdx.x - mbBlocks)*256 + threadIdx.x;
    if (e < Me){
      int s = eidx[e], d = eidx[Me + e];
      int p = atomicAdd(&cnt[d], 1);
      if (p < STRIDE) slot[(size_t)d*STRIDE + p] = (ushort)s;
    }
    return;
  }
  __shared__ ushort bt[128*64];           // Bt[c][k], XOR-swizzled
  __shared__ float stycS[2][4], stycD[2][4];
  int t = threadIdx.x;
  int wid = t >> 6, lane = t & 63, l15 = lane & 15, g = lane >> 4;
  int mbase = blockIdx.x*128 + wid*32;

  bf16x8 afr[2][2];
  #pragma unroll
  for (int mf=0; mf<2; mf++){
    int row = mbase + mf*16 + l15;
    int rc = row < Nn ? row : Nn-1;
    const ushort* ap = xb + (size_t)rc*64 + g*8;
    #pragma unroll
    for (int ks=0; ks<2; ks++)
      afr[mf][ks] = *(const bf16x8*)(ap + ks*32);
  }

  for (int idx = t; idx < 64*128; idx += 256){
    int k = idx >> 7, c = idx & 127;
    uint byte = ((uint)(c*64 + k) << 1) ^ ((uint)(c&7) << 4);
    *(ushort*)((char*)bt + byte) = f2bf(gw0[k*128 + c]);
  }

  if (t < 128){
    int c = t, h = c >> 5;
    float as_c = a_s[c], ad_c = a_d[c];
    float s0 = styleW0[c], s1 = styleW0[128 + c];
    float v0s = red32(s0*as_c), v0d = red32(s0*ad_c);
    float v1s = red32(s1*as_c), v1d = red32(s1*ad_c);
    if ((lane & 31) == 0){
      stycS[0][h] = v0s; stycD[0][h] = v0d;
      stycS[1][h] = v1s; stycD[1][h] = v1d;
    }
  }
  __syncthreads();

  f32x4 acc[2][8];
  #pragma unroll
  for (int mf=0; mf<2; mf++)
    #pragma unroll
    for (int nf=0; nf<8; nf++) acc[mf][nf] = (f32x4){0.f,0.f,0.f,0.f};

  #pragma unroll
  for (int ks=0; ks<2; ks++){
    int kb = ks*32 + g*8;
    bf16x8 bfr[8];
    #pragma unroll
    for (int nf=0; nf<8; nf++){
      int c = nf*16 + l15;
      uint byte = ((uint)(c*64 + kb) << 1) ^ ((uint)(c&7) << 4);
      bfr[nf] = *(const bf16x8*)((const char*)bt + byte);
    }
    #pragma unroll
    for (int mf=0; mf<2; mf++)
      #pragma unroll
      for (int nf=0; nf<8; nf++)
        acc[mf][nf] = __builtin_amdgcn_mfma_f32_16x16x32_bf16(
            afr[mf][ks], bfr[nf], acc[mf][nf], 0, 0, 0);
  }

  float sw0[8], sw1[8], as_v[8], ad_v[8];
  #pragma unroll
  for (int nf=0; nf<8; nf++){
    int c = nf*16 + l15;
    sw0[nf] = styleW0[c]; sw1[nf] = styleW0[128 + c];
    as_v[nf] = a_s[c];    ad_v[nf] = a_d[c];
  }
  #pragma unroll
  for (int mf=0; mf<2; mf++){
    int rbase = mbase + mf*16 + g*4;
    #pragma unroll
    for (int r=0; r<4; r++){
      int row = rbase + r;
      bool ok = (row < Nn);
      #pragma unroll
      for (int nf=0; nf<8; nf++){
        int c = nf*16 + l15;
        if (ok){
          float v = acc[mf][nf][r];
          ht0[(size_t)row*128 + c]      = f2f8(v + sw0[nf]);
          ht0[(size_t)(Nn+row)*128 + c] = f2f8(v + sw1[nf]);
        }
      }
      float ps0 = acc[mf][0][r]*as_v[0] + acc[mf][1][r]*as_v[1];
      float ps1 = acc[mf][2][r]*as_v[2] + acc[mf][3][r]*as_v[3];
      float ps2 = acc[mf][4][r]*as_v[4] + acc[mf][5][r]*as_v[5];
      float ps3 = acc[mf][6][r]*as_v[6] + acc[mf][7][r]*as_v[7];
      float pd0 = acc[mf][0][r]*ad_v[0] + acc[mf][1][r]*ad_v[1];
      float pd1 = acc[mf][2][r]*ad_v[2] + acc[mf][3][r]*ad_v[3];
      float pd2 = acc[mf][4][r]*ad_v[4] + acc[mf][5][r]*ad_v[5];
      float pd3 = acc[mf][6][r]*ad_v[6] + acc[mf][7][r]*ad_v[7];
      ps0 = red16(ps0); ps1 = red16(ps1); ps2 = red16(ps2); ps3 = red16(ps3);
      pd0 = red16(pd0); pd1 = red16(pd1); pd2 = red16(pd2); pd3 = red16(pd3);
      if (l15 == 0 && ok){
        *(float4*)(alS + (size_t)row*4) = make_float4(
            ps0 + stycS[0][0], ps1 + stycS[0][1], ps2 + stycS[0][2], ps3 + stycS[0][3]);
        *(float4*)(alD + (size_t)row*4) = make_float4(
            pd0 + stycD[0][0], pd1 + stycD[0][1], pd2 + stycD[0][2], pd3 + stycD[0][3]);
        *(float4*)(alS + (size_t)(Nn+row)*4) = make_float4(
            ps0 + stycS[1][0], ps1 + stycS[1][1], ps2 + stycS[1][2], ps3 + stycS[1][3]);
        *(float4*)(alD + (size_t)(Nn+row)*4) = make_float4(
            pd0 + stycD[1][0], pd1 + stycD[1][1], pd2 + stycD[1][2], pd3 + stycD[1][3]);
      }
    }
  }
}

// ---- MFMA matmul + fused attention logits; OUTPUT IS FP8 (aggregation input) ----
template<int NCOL, int LDO, int NF, int NHEAD>
__global__ __launch_bounds__(256) void k_mm_mfma(const ushort* __restrict__ A,
    const float* __restrict__ W, unsigned char* __restrict__ out,
    const float* __restrict__ a_s, const float* __restrict__ a_d,
    float* __restrict__ alS, float* __restrict__ alD, int M){
  constexpr int NCOLP = NF*16;
  __shared__ ushort bt[NCOLP*128];  // Bt[c][k], XOR-swizzled
  int t = threadIdx.x;
  int wid = t >> 6, lane = t & 63, l15 = lane & 15, g = lane >> 4;
  int mbase = blockIdx.x*128 + wid*32;

  bf16x8 afr[2][4];
  #pragma unroll
  for (int mf=0; mf<2; mf++){
    int row = mbase + mf*16 + l15;
    int rc = row < M ? row : M-1;
    const ushort* ap = A + (size_t)rc*128 + g*8;
    #pragma unroll
    for (int ks=0; ks<4; ks++)
      afr[mf][ks] = *(const bf16x8*)(ap + ks*32);
  }

  for (int idx = t; idx < 128*NCOLP; idx += 256){
    int k = idx / NCOLP, c = idx % NCOLP;
    float v = (c < NCOL) ? W[k*NCOL + c] : 0.f;
    uint byte = ((uint)(c*128 + k) << 1) ^ ((uint)(c&7) << 4);
    *(ushort*)((char*)bt + byte) = f2bf(v);
  }
  __syncthreads();

  f32x4 acc[2][NF];
  #pragma unroll
  for (int mf=0; mf<2; mf++)
    #pragma unroll
    for (int nf=0; nf<NF; nf++) acc[mf][nf] = (f32x4){0.f,0.f,0.f,0.f};

  #pragma unroll
  for (int ks=0; ks<4; ks++){
    int kb = ks*32 + g*8;
    bf16x8 bfr[NF];
    #pragma unroll
    for (int nf=0; nf<NF; nf++){
      int c = nf*16 + l15;
      uint byte = ((uint)(c*128 + kb) << 1) ^ ((uint)(c&7) << 4);
      bfr[nf] = *(const bf16x8*)((const char*)bt + byte);
    }
    #pragma unroll
    for (int mf=0; mf<2; mf++)
      #pragma unroll
      for (int nf=0; nf<NF; nf++)
        acc[mf][nf] = __builtin_amdgcn_mfma_f32_16x16x32_bf16(
            afr[mf][ks], bfr[nf], acc[mf][nf], 0, 0, 0);
  }

  // C/D layout: col = lane&15, row = (lane>>4)*4 + r
  #pragma unroll
  for (int mf=0; mf<2; mf++){
    int rbase = mbase + mf*16 + g*4;
    #pragma unroll
    for (int nf=0; nf<NF; nf++){
      int c = nf*16 + l15;
      if (c < LDO){
        #pragma unroll
        for (int r=0; r<4; r++){
          int row = rbase + r;
          if (row < M) out[(size_t)row*LDO + c] =
              (c < NCOL) ? f2f8(acc[mf][nf][r]) : (unsigned char)0;
        }
      }
    }
  }

  // fused per-row attention logits (from f32 accumulators)
  float as_v[NF], ad_v[NF];
  #pragma unroll
  for (int nf=0; nf<NF; nf++){
    int c = nf*16 + l15;
    as_v[nf] = (c < NCOL) ? a_s[c] : 0.f;
    ad_v[nf] = (c < NCOL) ? a_d[c] : 0.f;
  }
  #pragma unroll
  for (int mf=0; mf<2; mf++){
    #pragma unroll
    for (int r=0; r<4; r++){
      int row = mbase + mf*16 + g*4 + r;
      if constexpr (NHEAD == 4){
        float ps0 = acc[mf][0][r]*as_v[0] + acc[mf][1][r]*as_v[1];
        float ps1 = acc[mf][2][r]*as_v[2] + acc[mf][3][r]*as_v[3];
        float ps2 = acc[mf][4][r]*as_v[4] + acc[mf][5][r]*as_v[5];
        float ps3 = acc[mf][6][r]*as_v[6] + acc[mf][7][r]*as_v[7];
        float pd0 = acc[mf][0][r]*ad_v[0] + acc[mf][1][r]*ad_v[1];
        float pd1 = acc[mf][2][r]*ad_v[2] + acc[mf][3][r]*ad_v[3];
        float pd2 = acc[mf][4][r]*ad_v[4] + acc[mf][5][r]*ad_v[5];
        float pd3 = acc[mf][6][r]*ad_v[6] + acc[mf][7][r]*ad_v[7];
        ps0 = red16(ps0); ps1 = red16(ps1); ps2 = red16(ps2); ps3 = red16(ps3);
        pd0 = red16(pd0); pd1 = red16(pd1); pd2 = red16(pd2); pd3 = red16(pd3);
        if (l15 == 0 && row < M){
          *(float4*)(alS + (size_t)row*4) = make_float4(ps0, ps1, ps2, ps3);
          *(float4*)(alD + (size_t)row*4) = make_float4(pd0, pd1, pd2, pd3);
        }
      } else {
        float ps = 0.f, pd = 0.f;
        #pragma unroll
        for (int nf=0; nf<NF; nf++){
          ps += acc[mf][nf][r]*as_v[nf];
          pd += acc[mf][nf][r]*ad_v[nf];
        }
        ps = red16(ps); pd = red16(pd);
        if (l15 == 0 && row < M){
          alS[row] = ps; alD[row] = pd;
        }
      }
    }
  }
}

// ---------------- GAT aggregation layer 0/1: fp8 gathers, edge-pair lanes, 4 cols/lane ----------------
__global__ __launch_bounds__(256) void k_gat128(const unsigned char* __restrict__ ht,
    const float* __restrict__ alS, const float* __restrict__ alD,
    const int* __restrict__ deg, const ushort* __restrict__ slot,
    const float* __restrict__ gb, const float* __restrict__ lng,
    const float* __restrict__ lnb, ushort* __restrict__ outH, int n){
  __shared__ float wbuf[4][4][68];   // [wave][head][edge] padded
  __shared__ int   sbuf[4][64];
  int wave = threadIdx.x >> 6, lane = threadIdx.x & 63;
  int dd = blockIdx.x*4 + wave;
  if (dd >= n) return;
  int tr  = (dd >= Nn) ? dd - Nn : dd;
  int off = (dd >= Nn) ? Nn : 0;
  int sub = lane >> 5, li = lane & 31;
  int c0 = li*4;
  int h  = li >> 3;
  float4 ald4 = *(const float4*)(alD + dd*4);
  int dg = deg[tr]; if (dg > STRIDE) dg = STRIDE;
  int begin = tr*STRIDE, end = begin + dg;

  // self-loop term (added by sub==0 half only)
  float4 asl = *(const float4*)(alS + dd*4);
  float4 wsl;
  wsl.x = __expf(leaky(asl.x + ald4.x));
  wsl.y = __expf(leaky(asl.y + ald4.y));
  wsl.z = __expf(leaky(asl.z + ald4.z));
  wsl.w = __expf(leaky(asl.w + ald4.w));
  float es = sel4(wsl, h);
  float acc0=0.f, acc1=0.f, acc2=0.f, acc3=0.f, den=0.f;
  if (sub == 0){
    uint sv = *(const uint*)(ht + (size_t)dd*128 + c0);
    f32x2 lo = f8x2f<false>(sv), hi = f8x2f<true>(sv);
    den = es;
    acc0 = es * lo.x; acc1 = es * lo.y;
    acc2 = es * hi.x; acc3 = es * hi.y;
  }

  const unsigned char* __restrict__ htp = ht + c0;

  for (int j = begin; j < end; j += 64){
    int nc = min(64, end - j);
    if (lane < nc){
      int s = (int)slot[j + lane] + off;
      float4 as4 = *(const float4*)(alS + s*4);
      wbuf[wave][0][lane] = __expf(leaky(as4.x + ald4.x));
      wbuf[wave][1][lane] = __expf(leaky(as4.y + ald4.y));
      wbuf[wave][2][lane] = __expf(leaky(as4.z + ald4.z));
      wbuf[wave][3][lane] = __expf(leaky(as4.w + ald4.w));
      sbuf[wave][lane] = s;
    }
    const float* __restrict__ wh = wbuf[wave][h];
    int q = 0;
    for (; q + 8 <= nc; q += 8){
      int sv[4]; float wv[4];
      #pragma unroll
      for (int u=0;u<4;u++){ int e = q + 2*u + sub; sv[u] = sbuf[wave][e]; wv[u] = wh[e]; }
      uint hv[4];
      #pragma unroll
      for (int u=0;u<4;u++) hv[u] = *(const uint*)(htp + (size_t)sv[u]*128);
      #pragma unroll
      for (int u=0;u<4;u++){
        f32x2 lo = f8x2f<false>(hv[u]), hi = f8x2f<true>(hv[u]);
        den  += wv[u];
        acc0 += wv[u] * lo.x; acc1 += wv[u] * lo.y;
        acc2 += wv[u] * hi.x; acc3 += wv[u] * hi.y;
      }
    }
    for (; q < nc; q += 2){
      int e = q + sub;
      if (e < nc){
        int s = sbuf[wave][e];
        float w = wh[e];
        uint hv = *(const uint*)(htp + (size_t)s*128);
        f32x2 lo = f8x2f<false>(hv), hi = f8x2f<true>(hv);
        den  += w;
        acc0 += w * lo.x; acc1 += w * lo.y;
        acc2 += w * hi.x; acc3 += w * hi.y;
      }
    }
  }
  acc0 += __shfl_xor(acc0, 32); acc1 += __shfl_xor(acc1, 32);
  acc2 += __shfl_xor(acc2, 32); acc3 += __shfl_xor(acc3, 32);
  den  += __shfl_xor(den, 32);

  float idn = 1.f / (den + 1e-16f);
  float4 gbv = *(const float4*)(gb + c0);
  float v0 = acc0*idn + gbv.x;
  float v1 = acc1*idn + gbv.y;
  float v2 = acc2*idn + gbv.z;
  float v3 = acc3*idn + gbv.w;

  float sum = v0+v1+v2+v3;
  float sq  = v0*v0+v1*v1+v2*v2+v3*v3;
  sum = red32(sum); sq = red32(sq);
  float mu  = sum * (1.f/128.f);
  float var = sq  * (1.f/128.f) - mu*mu;
  float inv = rsqrtf(var + 1e-5f);
  float4 lg = *(const float4*)(lng + c0);
  float4 lb = *(const float4*)(lnb + c0);
  if (sub == 0){
    float y0 = (v0 - mu)*inv*lg.x + lb.x;
    float y1 = (v1 - mu)*inv*lg.y + lb.y;
    float y2 = (v2 - mu)*inv*lg.z + lb.z;
    float y3 = (v3 - mu)*inv*lg.w + lb.w;
    uint2 ow;
    ow.x = (uint)f2bf(leaky(y0)) | ((uint)f2bf(leaky(y1)) << 16);
    ow.y = (uint)f2bf(leaky(y2)) | ((uint)f2bf(leaky(y3)) << 16);
    *(uint2*)(outH + (size_t)dd*128 + c0) = ow;
  }
}

// ---------------- GAT output layer (1 head, 67 cols), fp8 gathers + residual ----------------
__global__ __launch_bounds__(256) void k_gat_out(const unsigned char* __restrict__ ht2,
    const float* __restrict__ alS, const float* __restrict__ alD,
    const int* __restrict__ deg, const ushort* __restrict__ slot,
    const float* __restrict__ gb2, const float* __restrict__ x,
    const float* __restrict__ pos, float* __restrict__ out, int n){
  __shared__ float wbuf[4][64];
  __shared__ int   sbuf[4][64];
  int wave = threadIdx.x >> 6, lane = threadIdx.x & 63;
  int dd = blockIdx.x*4 + wave;
  if (dd >= n) return;
  int tr  = (dd >= Nn) ? dd - Nn : dd;
  int off = (dd >= Nn) ? Nn : 0;
  int c0 = lane*2;
  bool act = (c0 < 67);             // lane < 34
  float ald = alD[dd];
  int dg = deg[tr]; if (dg > STRIDE) dg = STRIDE;
  int begin = tr*STRIDE, end = begin + dg;

  float wsl = __expf(leaky(alS[dd] + ald));
  float den  = wsl;
  uint sv0 = act ? (uint)*(const ushort*)(ht2 + (size_t)dd*68 + c0) : 0u;
  f32x2 sd = f8x2f<false>(sv0);
  float acc0 = wsl * sd.x;
  float acc1 = wsl * sd.y;

  const unsigned char* __restrict__ h2p = ht2 + c0;

  for (int j = begin; j < end; j += 64){
    int nc = min(64, end - j);
    if (lane < nc){
      int s = (int)slot[j + lane] + off;
      wbuf[wave][lane] = __expf(leaky(alS[s] + ald));
      sbuf[wave][lane] = s;
    }
    int q = 0;
    for (; q + 8 <= nc; q += 8){
      int sv[8]; float wv[8];
      #pragma unroll
      for (int u=0;u<8;u++){ sv[u] = sbuf[wave][q+u]; wv[u] = wbuf[wave][q+u]; }
      uint hv[8];
      #pragma unroll
      for (int u=0;u<8;u++) hv[u] = act ? (uint)*(const ushort*)(h2p + (size_t)sv[u]*68) : 0u;
      #pragma unroll
      for (int u=0;u<8;u++){
        f32x2 d = f8x2f<false>(hv[u]);
        den  += wv[u];
        acc0 += wv[u] * d.x;
        acc1 += wv[u] * d.y;
      }
    }
    for (; q < nc; q++){
      int s = sbuf[wave][q]; float w = wbuf[wave][q];
      uint hv = act ? (uint)*(const ushort*)(h2p + (size_t)s*68) : 0u;
      f32x2 d = f8x2f<false>(hv);
      den  += w;
      acc0 += w * d.x;
      acc1 += w * d.y;
    }
  }
  if (!act) return;
  float idn = 1.f / (den + 1e-16f);
  int i = tr;
  int c1 = c0 + 1;
  float v0 = acc0*idn + gb2[c0];
  if (c0 < 3) out[NT*64 + dd*3 + c0] = pos[i*3 + c0] + v0;
  else        out[dd*64 + (c0-3)]    = x[i*64 + (c0-3)] + v0;
  if (c1 < 67){
    float v1 = acc1*idn + gb2[c1];
    if (c1 < 3) out[NT*64 + dd*3 + c1] = pos[i*3 + c1] + v1;
    else        out[dd*64 + (c1-3)]    = x[i*64 + (c1-3)] + v1;
  }
}

extern "C" void kernel_launch(void* const* d_in, const int* in_sizes, int n_in,
                              void* d_out, int out_size, void* d_ws, size_t ws_size,
                              hipStream_t stream){
  const float* z    = (const float*)d_in[0];
  const float* x    = (const float*)d_in[1];
  const float* pos  = (const float*)d_in[2];
  const int*   eidx = (const int*)  d_in[3];
  const float* w1   = (const float*)d_in[4];
  const float* b1   = (const float*)d_in[5];
  const float* w2   = (const float*)d_in[6];
  const float* b2   = (const float*)d_in[7];
  const float* w3   = (const float*)d_in[8];
  const float* b3   = (const float*)d_in[9];
  const float* gw0  = (const float*)d_in[10];
  const float* ga0s = (const float*)d_in[11];
  const float* ga0d = (const float*)d_in[12];
  const float* gb0  = (const float*)d_in[13];
  const float* gw1  = (const float*)d_in[14];
  const float* ga1s = (const float*)d_in[15];
  const float* ga1d = (const float*)d_in[16];
  const float* gb1  = (const float*)d_in[17];
  const float* gw2  = (const float*)d_in[18];
  const float* ga2s = (const float*)d_in[19];
  const float* ga2d = (const float*)d_in[20];
  const float* gb2  = (const float*)d_in[21];
  const float* ln0g = (const float*)d_in[22];
  const float* ln0b = (const float*)d_in[23];
  const float* ln1g = (const float*)d_in[24];
  const float* ln1b = (const float*)d_in[25];
  float* out = (float*)d_out;

  float* ws       = (float*)d_ws;
  float* styleW0  = ws;                  // 256
  float* s1buf    = ws + 256;            // 512
  float* s2buf    = s1buf + 512;         // 1024
  float* Mbuf     = s2buf + 1024;        // 512*128
  float* bGbuf    = Mbuf + 512*128;      // 128
  float* alS      = bGbuf + 128;         // 80000
  float* alD      = alS + 80000;         // 80000
  unsigned char* htA = (unsigned char*)(alD + 80000); // NT*128 fp8
  ushort* htB     = (ushort*)(htA + (size_t)NT*128);  // NT*128 bf16
  unsigned char* ht2c = (unsigned char*)(htB + (size_t)NT*128); // NT*68 fp8
  ushort* xb      = (ushort*)(ht2c + (size_t)NT*68);  // Nn*64 bf16
  int*   cnt      = (int*)(xb + (size_t)Nn*64);       // Nn (degree)
  ushort* slot    = (ushort*)(cnt + Nn);              // Nn*STRIDE (padded CSR)

  const float* G = gw0 + 64*128;           // style half of gw0

  // dispatch 1: style stage1 + tails {zero cnt, x->bf16, M=w3@G, bG=b3@G}
  const int ZB = (Nn + 255)/256;           // 40
  const int XB = (Nn*64/4 + 255)/256;      // 625
  const int MBk = 256;                     // 512 k-rows / 2 per block
  k_mlp<128><<<128 + ZB + XB + MBk + 1, 256, 0, stream>>>(
      z, w1, b1, s1buf, 256, 1, 128,
      cnt, Nn, ZB, x, xb, Nn*64/4, XB,
      w3, G, Mbuf, b3, bGbuf, MBk);
  // stage 2
  k_mlp<256><<<256, 256, 0, stream>>>(s1buf, w2, b2, s2buf, 512, 1, 256,
      nullptr, 0, 0, nullptr, nullptr, 0, 0, nullptr, nullptr, nullptr, nullptr, nullptr, 0);
  // fused stages 3+4: styleW0 = s2 @ M + bG
  k_mlp<512><<<64, 256, 0, stream>>>(s2buf, Mbuf, bGbuf, styleW0, 128, 0, 64,
      nullptr, 0, 0, nullptr, nullptr, 0, 0, nullptr, nullptr, nullptr, nullptr, nullptr, 0);

  const int MB0 = (Nn+127)/128;            // 79 mfma blocks
  const int EB  = (Me+255)/256;            // 1250 scatter blocks
  // layer 0: ht0 MFMA (fp8 out) + fused logits, CSR scatter in extra blocks
  k_ht0_mfma<<<MB0 + EB, 256, 0, stream>>>(xb, gw0, styleW0, ga0s, ga0d,
                                           htA, alS, alD, MB0, eidx, cnt, slot);
  k_gat128<<<(NT+3)/4, 256, 0, stream>>>(htA, alS, alD, cnt, slot,
                                         gb0, ln0g, ln0b, htB, NT);
  // layer 1 (matmul + fused logits; fp8 out)
  const int MB = (NT+127)/128;
  k_mm_mfma<128,128,8,4><<<MB, 256, 0, stream>>>(htB, gw1, htA, ga1s, ga1d, alS, alD, NT);
  k_gat128<<<(NT+3)/4, 256, 0, stream>>>(htA, alS, alD, cnt, slot,
                                         gb1, ln1g, ln1b, htB, NT);
  // layer 2 (matmul + fused logits, 1 head, fp8 out; then fused residual + final write)
  k_mm_mfma<67,68,5,1><<<MB, 256, 0, stream>>>(htB, gw2, ht2c, ga2s, ga2d, alS, alD, NT);
  k_gat_out<<<(NT+3)/4, 256, 0, stream>>>(ht2c, alS, alD, cnt, slot,
                                          gb2, x, pos, out, NT);
}